// Round 13
// baseline (235.493 us; speedup 1.0000x reference)
//
#include <hip/hip_runtime.h>
#include <hip/hip_bf16.h>
#include <math.h>
#include <stdint.h>

typedef _Float16 f16;
typedef _Float16 f16x8 __attribute__((ext_vector_type(8)));
typedef float f32x16 __attribute__((ext_vector_type(16)));

#define DIM 256
#define LOSCALE 2048.0f
#define INV_LOSCALE (1.0f/2048.0f)

// B' stream: 4096 codes x 256 depth x {hi,lo}, fragment-major:
// byte offset = col*32768 + s*2048 + t*1024 + lane*16
// (col 0..127 = 32 codes each, k-step s 0..15, t 0:hi 1:lo)
// lane l holds 16B = e[code=col*32+(l&31)][depth=s*16+(l>>5)*8 .. +8]
// 96KB pad: staging runs 2 cols past each half's end.
#define BP_BYTES (4096u*1024u + 98304u)

#define GLOAD16(gp, lp) __builtin_amdgcn_global_load_lds( \
    (const __attribute__((address_space(1))) void*)(gp),  \
    (__attribute__((address_space(3))) void*)(lp), 16, 0, 0)

// ---------------------------------------------------------------------------
// pack codebook into fragment-major hi/lo f16 stream
// ---------------------------------------------------------------------------
__global__ void vq_pack2(const float* __restrict__ emb, f16* __restrict__ bp)
{
    int o = blockIdx.x * blockDim.x + threadIdx.x;   // one per 16B chunk, 262144
    int l = o & 63;
    int b = o >> 6;
    int t   = b & 1;
    int s   = (b >> 1) & 15;
    int col = b >> 5;
    int code  = col * 32 + (l & 31);
    int depth = s * 16 + (l >> 5) * 8;
    const float* gp = emb + (size_t)code * DIM + depth;
    float4 x0 = *(const float4*)gp;
    float4 x1 = *(const float4*)(gp + 4);
    float xs[8] = {x0.x, x0.y, x0.z, x0.w, x1.x, x1.y, x1.z, x1.w};
    f16x8 v;
    #pragma unroll
    for (int j = 0; j < 8; ++j) {
        f16 h = (f16)xs[j];
        v[j] = t ? (f16)((xs[j] - (float)h) * LOSCALE) : h;
    }
    *(f16x8*)(bp + (size_t)o * 8) = v;
}

// ||e_k||^2, one 64-thread block per code (fp32, full precision)
__global__ void vq_e2(const float* __restrict__ emb, float* __restrict__ e2) {
    int k = blockIdx.x;
    int l = threadIdx.x;
    float4 v = ((const float4*)(emb + (size_t)k * DIM))[l];
    float s = v.x * v.x + v.y * v.y + v.z * v.z + v.w * v.w;
    #pragma unroll
    for (int off = 32; off; off >>= 1) s += __shfl_xor(s, off);
    if (l == 0) e2[k] = s;
}

__global__ void vq_zero(int* __restrict__ p, int n) {
    int i = blockIdx.x * blockDim.x + threadIdx.x;
    if (i < n) p[i] = 0;
}

// ---------------------------------------------------------------------------
// MFMA argmin, m201-style burst phases: per col, 4 phases of 4 k-steps.
// Phase = {1 gload_lds stage; [vmcnt(5) ph0]; 8 ds_read -> regs;
//          barrier; lgkmcnt(0); 12 PURE-REG MFMA; barrier}.
// Reads issued pre-barrier complete during other waves' MFMA bursts ->
// LDS pipe and matrix pipe overlap CU-wide instead of alternating per-wave.
// 512 thr = 8 waves x 32 rows, one code half; 4 x 32KB bufs, vmcnt counted.
// ---------------------------------------------------------------------------
__global__ __launch_bounds__(512, 2) void vq_argmin12(
    const float* __restrict__ z, const char* __restrict__ bp,
    const float* __restrict__ e2, unsigned long long* __restrict__ part)
{
    __shared__ __align__(16) char bufs[4][32768];   // 128 KB
    __shared__ float e2s[2048];                     // 8 KB

    const int t    = threadIdx.x;
    const int lane = t & 63;
    const int wv   = t >> 6;               // wave 0..7
    const int hw   = blockIdx.x & 1;       // code half
    const int rg   = blockIdx.x >> 1;      // row group (256 rows)
    const int l31  = lane & 31;
    const int hi5  = lane >> 5;
    const int rowbase = rg * 256 + wv * 32;

    // ---- e2 half to LDS ----
    *(float4*)&e2s[t * 4] = *(const float4*)(e2 + hw * 2048 + t * 4);

    // ---- A panel (32 rows) to registers, hi/lo split ----
    f16x8 a_h[16], a_l[16];
    {
        const float* zr = z + (size_t)(rowbase + l31) * DIM + hi5 * 8;
        #pragma unroll
        for (int s = 0; s < 16; ++s) {
            float4 x0 = *(const float4*)(zr + s * 16);
            float4 x1 = *(const float4*)(zr + s * 16 + 4);
            float xs[8] = {x0.x, x0.y, x0.z, x0.w, x1.x, x1.y, x1.z, x1.w};
            #pragma unroll
            for (int j = 0; j < 8; ++j) {
                f16 h = (f16)xs[j];
                a_h[s][j] = h;
                a_l[s][j] = (f16)((xs[j] - (float)h) * LOSCALE);
            }
        }
    }

    const char* bhalf = bp + ((size_t)hw << 21);   // 2 MB half

    // full-col stage (prologue only): 512 thr x 4 x 16B = 32KB
#define STAGEF(pb, cc) do {                                                   \
    const char* src_ = bhalf + ((size_t)(cc) << 15) + (size_t)t * 16;         \
    char* dst_ = bufs[pb] + t * 16;                                           \
    _Pragma("unroll")                                                         \
    for (int i_ = 0; i_ < 4; ++i_)                                            \
        GLOAD16(src_ + i_ * 8192, dst_ + i_ * 8192);                          \
    } while (0)

    // per-phase stage: quarter col (8KB), one gload per thread
#define STAGE1(pb, cc, g) do {                                                \
    const char* src_ = bhalf + ((size_t)(cc) << 15) + (size_t)t * 16          \
                     + (size_t)(g) * 8192;                                    \
    char* dst_ = bufs[pb] + t * 16 + (g) * 8192;                              \
    GLOAD16(src_, dst_);                                                      \
    } while (0)

    // one burst phase: stage quarter of col c+2, read group g to regs
    // (pre-barrier), then pure-reg MFMA cluster (post-barrier).
#define PHASE(g) do {                                                         \
    STAGE1((c + 2) & 3, c + 2, g);                                            \
    if ((g) == 0) asm volatile("s_waitcnt vmcnt(5)" ::: "memory");            \
    _Pragma("unroll")                                                         \
    for (int j_ = 0; j_ < 4; ++j_) {                                          \
        rh[j_] = *(const f16x8*)(bb + ((g) * 4 + j_) * 2048 + lane * 16);     \
        rl[j_] = *(const f16x8*)(bb + ((g) * 4 + j_) * 2048 + 1024 + lane * 16); \
    }                                                                         \
    __builtin_amdgcn_sched_barrier(0);                                        \
    __builtin_amdgcn_s_barrier();                                             \
    asm volatile("s_waitcnt lgkmcnt(0)" ::: "memory");                        \
    __builtin_amdgcn_sched_barrier(0);                                        \
    __builtin_amdgcn_s_setprio(1);                                            \
    _Pragma("unroll")                                                         \
    for (int j_ = 0; j_ < 4; ++j_) {                                          \
        const int ks_ = (g) * 4 + j_;                                         \
        acc0  = __builtin_amdgcn_mfma_f32_32x32x16_f16(a_h[ks_], rh[j_], acc0,  0,0,0); \
        acc1a = __builtin_amdgcn_mfma_f32_32x32x16_f16(a_h[ks_], rl[j_], acc1a, 0,0,0); \
        acc1b = __builtin_amdgcn_mfma_f32_32x32x16_f16(a_l[ks_], rh[j_], acc1b, 0,0,0); \
    }                                                                         \
    __builtin_amdgcn_s_setprio(0);                                            \
    __builtin_amdgcn_sched_barrier(0);                                        \
    __builtin_amdgcn_s_barrier();                                             \
    } while (0)

    STAGEF(0, 0);
    STAGEF(1, 1);
    __syncthreads();   // full drain once: cols 0,1 staged; e2s visible

    float    bestd[16];
    unsigned bcol[4];
    #pragma unroll
    for (int q = 0; q < 16; ++q) bestd[q] = 3.4e38f;
    #pragma unroll
    for (int i = 0; i < 4; ++i) bcol[i] = 0u;

    for (int c = 0; c < 64; ++c) {
        const char* bb = bufs[c & 3];
        f32x16 acc0, acc1a, acc1b;
        #pragma unroll
        for (int q = 0; q < 16; ++q) { acc0[q] = 0.0f; acc1a[q] = 0.0f; acc1b[q] = 0.0f; }

        f16x8 rh[4], rl[4];
        PHASE(0);
        PHASE(1);
        PHASE(2);
        PHASE(3);

        // epilogue: fold scales, distances, running argmin
        float e2c = e2s[c * 32 + l31];
        #pragma unroll
        for (int q = 0; q < 16; ++q) {
            float dot  = fmaf(acc1a[q] + acc1b[q], INV_LOSCALE, acc0[q]);
            float dist = fmaf(-2.0f, dot, e2c);
            bool  lt   = dist < bestd[q];
            bestd[q]   = lt ? dist : bestd[q];
            const unsigned sh = (unsigned)((q & 3) * 8);
            unsigned nv = (bcol[q >> 2] & ~(0xFFu << sh)) | ((unsigned)c << sh);
            bcol[q >> 2] = lt ? nv : bcol[q >> 2];
        }
    }
#undef STAGEF
#undef STAGE1
#undef PHASE

    // ---- per-wave reduce across 32 code-lanes; write partial keys ----
    #pragma unroll
    for (int q = 0; q < 16; ++q) {
        float    d = bestd[q];
        unsigned c = (unsigned)(hw * 2048) +
                     ((bcol[q >> 2] >> ((q & 3) * 8)) & 0xFFu) * 32u + (unsigned)l31;
        #pragma unroll
        for (int o2 = 16; o2; o2 >>= 1) {
            float    od = __shfl_xor(d, o2);
            unsigned oc = __shfl_xor(c, o2);
            if (od < d || (od == d && oc < c)) { d = od; c = oc; }
        }
        if (l31 == 0) {
            int row = (q & 3) + 8 * (q >> 2) + 4 * hi5;
            unsigned u   = __float_as_uint(d);
            unsigned key = u ^ (unsigned)(((int)u >> 31) | 0x80000000);
            part[(size_t)hw * 32768 + rowbase + row] =
                ((unsigned long long)key << 32) | c;
        }
    }
}

// fused: combine half-K partials -> idx, gather z_q row, histogram
__global__ void vq_final(const unsigned long long* __restrict__ part,
                         const float* __restrict__ emb,
                         float* __restrict__ idxf, float* __restrict__ zq,
                         int* __restrict__ counts, int N)
{
    int n = blockIdx.x * 4 + (threadIdx.x >> 6);
    int l = threadIdx.x & 63;
    if (n >= N) return;
    unsigned long long a = part[n];
    unsigned long long b = part[(size_t)N + n];
    unsigned long long m = b < a ? b : a;
    int idx = (int)(unsigned)(m & 0xffffffffu);
    ((float4*)(zq + (size_t)n * DIM))[l] =
        ((const float4*)(emb + (size_t)idx * DIM))[l];
    if (l == 0) {
        idxf[n] = (float)idx;
        atomicAdd(&counts[idx], 1);
    }
}

// ------------------------- round-1 fallback argmin -------------------------
__global__ __launch_bounds__(256, 2) void vq_argmin_f32(
    const float* __restrict__ z, const float* __restrict__ emb,
    const float* __restrict__ e2, float* __restrict__ idxf, int K)
{
    __shared__ float zs[64 * 36];
    __shared__ float es[128 * 36];
    const int t = threadIdx.x;
    const int tx = t & 15;
    const int ty = t >> 4;
    const int rowbase = blockIdx.x * 64;
    const float* zbase = z + (size_t)rowbase * DIM;
    float best[4]; int bidx[4];
    #pragma unroll
    for (int i = 0; i < 4; ++i) { best[i] = 3.4e38f; bidx[i] = 0; }
    for (int kt = 0; kt < K; kt += 128) {
        float acc[4][8];
        #pragma unroll
        for (int i = 0; i < 4; ++i)
            #pragma unroll
            for (int j = 0; j < 8; ++j) acc[i][j] = 0.0f;
        for (int dc = 0; dc < DIM; dc += 32) {
            { int lr = t >> 2, o = (t & 3) * 8;
              const float* gp = zbase + (size_t)lr * DIM + dc + o;
              *(float4*)&zs[lr*36+o]   = *(const float4*)gp;
              *(float4*)&zs[lr*36+o+4] = *(const float4*)(gp+4); }
            { int lc = t >> 1, o = (t & 1) * 16;
              const float* gp = emb + (size_t)(kt+lc) * DIM + dc + o;
              *(float4*)&es[lc*36+o]    = *(const float4*)gp;
              *(float4*)&es[lc*36+o+4]  = *(const float4*)(gp+4);
              *(float4*)&es[lc*36+o+8]  = *(const float4*)(gp+8);
              *(float4*)&es[lc*36+o+12] = *(const float4*)(gp+12); }
            __syncthreads();
            const float* zp = &zs[(ty*4)*36];
            const float* ep = &es[tx*36];
            #pragma unroll
            for (int d = 0; d < 32; d += 4) {
                float4 zv[4], ev[8];
                #pragma unroll
                for (int i = 0; i < 4; ++i) zv[i] = *(const float4*)&zp[i*36+d];
                #pragma unroll
                for (int j = 0; j < 8; ++j) ev[j] = *(const float4*)&ep[j*16*36+d];
                #pragma unroll
                for (int i = 0; i < 4; ++i)
                    #pragma unroll
                    for (int j = 0; j < 8; ++j) {
                        acc[i][j] += zv[i].x*ev[j].x; acc[i][j] += zv[i].y*ev[j].y;
                        acc[i][j] += zv[i].z*ev[j].z; acc[i][j] += zv[i].w*ev[j].w;
                    }
            }
            __syncthreads();
        }
        #pragma unroll
        for (int j = 0; j < 8; ++j) {
            int c = kt + tx + 16*j;
            float ev2 = e2[c];
            #pragma unroll
            for (int i = 0; i < 4; ++i) {
                float dist = ev2 - 2.0f*acc[i][j];
                if (dist < best[i] || (dist == best[i] && c < bidx[i])) { best[i]=dist; bidx[i]=c; }
            }
        }
    }
    #pragma unroll
    for (int i = 0; i < 4; ++i) {
        float bd = best[i]; int bi = bidx[i];
        #pragma unroll
        for (int off = 8; off; off >>= 1) {
            float od = __shfl_xor(bd, off); int oi = __shfl_xor(bi, off);
            if (od < bd || (od == bd && oi < bi)) { bd = od; bi = oi; }
        }
        if (tx == 0) idxf[rowbase + ty*4 + i] = (float)bi;
    }
}

// ------------------------------ epilogue ops -------------------------------
__global__ void vq_gather(const float* __restrict__ emb,
                          const float* __restrict__ idxf,
                          float* __restrict__ zq, int N)
{
    int n = blockIdx.x * 4 + (threadIdx.x >> 6);
    int l = threadIdx.x & 63;
    if (n >= N) return;
    int idx = (int)idxf[n];
    ((float4*)(zq + (size_t)n * DIM))[l] = ((const float4*)(emb + (size_t)idx * DIM))[l];
}

__global__ void vq_hist(const float* __restrict__ idxf, int* __restrict__ counts, int N) {
    int n = blockIdx.x * blockDim.x + threadIdx.x;
    if (n < N) atomicAdd(&counts[(int)idxf[n]], 1);
}

__global__ void vq_ppl(const int* __restrict__ counts, float invN,
                       float* __restrict__ out, int K)
{
    int t = threadIdx.x;
    float s = 0.0f;
    for (int k = t; k < K; k += 256) {
        float p = (float)counts[k] * invN;
        s += p * logf(p + 1e-10f);
    }
    #pragma unroll
    for (int off = 32; off; off >>= 1) s += __shfl_xor(s, off);
    __shared__ float wsum[4];
    if ((t & 63) == 0) wsum[t >> 6] = s;
    __syncthreads();
    if (t == 0) out[0] = expf(-(wsum[0] + wsum[1] + wsum[2] + wsum[3]));
}

extern "C" void kernel_launch(void* const* d_in, const int* in_sizes, int n_in,
                              void* d_out, int out_size, void* d_ws, size_t ws_size,
                              hipStream_t stream)
{
    const float* z   = (const float*)d_in[0];
    const float* emb = (const float*)d_in[1];
    const int N = in_sizes[0] / DIM;   // 32768
    const int K = in_sizes[1] / DIM;   // 4096

    float* out  = (float*)d_out;
    float* zq   = out;
    float* idxf = out + (size_t)N * DIM;
    float* ppl  = idxf + N;

    const size_t PART_BYTES = 2ull * 32768 * sizeof(unsigned long long);  // 512 KB
    const size_t NEED = (size_t)BP_BYTES + 16384 + 16384 + PART_BYTES;

    if (ws_size >= NEED && K == 4096 && N == 32768) {
        f16*   bpk    = (f16*)d_ws;
        float* e2     = (float*)((char*)d_ws + BP_BYTES);
        int*   counts = (int*)((char*)d_ws + BP_BYTES + 16384);
        unsigned long long* part =
            (unsigned long long*)((char*)d_ws + BP_BYTES + 32768);

        vq_pack2<<<1024, 256, 0, stream>>>(emb, bpk);
        vq_e2<<<K, 64, 0, stream>>>(emb, e2);
        vq_zero<<<(K + 255) / 256, 256, 0, stream>>>(counts, K);
        vq_argmin12<<<(N / 256) * 2, 512, 0, stream>>>(z, (const char*)bpk, e2, part);
        vq_final<<<N / 4, 256, 0, stream>>>(part, emb, idxf, zq, counts, N);
        vq_ppl<<<1, 256, 0, stream>>>(counts, 1.0f / (float)N, ppl, K);
    } else {
        float* e2     = (float*)d_ws;
        int*   counts = (int*)((char*)d_ws + (size_t)K * sizeof(float));
        vq_e2<<<K, 64, 0, stream>>>(emb, e2);
        vq_zero<<<(K + 255) / 256, 256, 0, stream>>>(counts, K);
        vq_argmin_f32<<<N / 64, 256, 0, stream>>>(z, emb, e2, idxf, K);
        vq_gather<<<N / 4, 256, 0, stream>>>(emb, idxf, zq, N);
        vq_hist<<<(N + 255) / 256, 256, 0, stream>>>(idxf, counts, N);
        vq_ppl<<<1, 256, 0, stream>>>(counts, 1.0f / (float)N, ppl, K);
    }
}

// Round 14
// 234.795 us; speedup vs baseline: 1.0030x; 1.0030x over previous
//
#include <hip/hip_runtime.h>
#include <hip/hip_bf16.h>
#include <math.h>
#include <stdint.h>

typedef _Float16 f16;
typedef _Float16 f16x8 __attribute__((ext_vector_type(8)));
typedef float f32x16 __attribute__((ext_vector_type(16)));

#define DIM 256
#define LOSCALE 2048.0f
#define INV_LOSCALE (1.0f/2048.0f)

// B' stream: 4096 codes x 256 depth x {hi,lo}, fragment-major:
// byte offset = col*32768 + s*2048 + t*1024 + lane*16
// (col 0..127 = 32 codes each, k-step s 0..15, t 0:hi 1:lo)
// lane l holds 16B = e[code=col*32+(l&31)][depth=s*16+(l>>5)*8 .. +8]
// 96KB pad: staging runs 2 cols past each half's end.
#define BP_BYTES (4096u*1024u + 98304u)

#define GLOAD16(gp, lp) __builtin_amdgcn_global_load_lds( \
    (const __attribute__((address_space(1))) void*)(gp),  \
    (__attribute__((address_space(3))) void*)(lp), 16, 0, 0)

// ---------------------------------------------------------------------------
// pack codebook into fragment-major hi/lo f16 stream
// ---------------------------------------------------------------------------
__global__ void vq_pack2(const float* __restrict__ emb, f16* __restrict__ bp)
{
    int o = blockIdx.x * blockDim.x + threadIdx.x;   // one per 16B chunk, 262144
    int l = o & 63;
    int b = o >> 6;
    int t   = b & 1;
    int s   = (b >> 1) & 15;
    int col = b >> 5;
    int code  = col * 32 + (l & 31);
    int depth = s * 16 + (l >> 5) * 8;
    const float* gp = emb + (size_t)code * DIM + depth;
    float4 x0 = *(const float4*)gp;
    float4 x1 = *(const float4*)(gp + 4);
    float xs[8] = {x0.x, x0.y, x0.z, x0.w, x1.x, x1.y, x1.z, x1.w};
    f16x8 v;
    #pragma unroll
    for (int j = 0; j < 8; ++j) {
        f16 h = (f16)xs[j];
        v[j] = t ? (f16)((xs[j] - (float)h) * LOSCALE) : h;
    }
    *(f16x8*)(bp + (size_t)o * 8) = v;
}

// ||e_k||^2, one 64-thread block per code (fp32, full precision)
__global__ void vq_e2(const float* __restrict__ emb, float* __restrict__ e2) {
    int k = blockIdx.x;
    int l = threadIdx.x;
    float4 v = ((const float4*)(emb + (size_t)k * DIM))[l];
    float s = v.x * v.x + v.y * v.y + v.z * v.z + v.w * v.w;
    #pragma unroll
    for (int off = 32; off; off >>= 1) s += __shfl_xor(s, off);
    if (l == 0) e2[k] = s;
}

__global__ void vq_zero(int* __restrict__ p, int n) {
    int i = blockIdx.x * blockDim.x + threadIdx.x;
    if (i < n) p[i] = 0;
}

// ---------------------------------------------------------------------------
// MFMA argmin: r10 skeleton + 6 independent accumulator chains.
// Theory: dependent-MFMA issue latency L ~ 100 cyc; with only 3 chains/wave
// the same chain recurs every ~24 cyc of pipe time -> wave stalls, util ~50%
// (observed r7-r13). Six chains/wave (m0,m1 mains even/odd; c0..c3
// corrections) put same-chain issues 6 MFMA = 48 cyc apart per wave, 96 cyc
// per SIMD at 2 waves -> pipe fills.
// 512 thr = 8 waves x 32 rows, one code half; 4 x 32KB bufs, vmcnt(8).
// ---------------------------------------------------------------------------
__global__ __launch_bounds__(512, 2) void vq_argmin13(
    const float* __restrict__ z, const char* __restrict__ bp,
    const float* __restrict__ e2, unsigned long long* __restrict__ part)
{
    __shared__ __align__(16) char bufs[4][32768];   // 128 KB
    __shared__ float e2s[2048];                     // 8 KB

    const int t    = threadIdx.x;
    const int lane = t & 63;
    const int wv   = t >> 6;               // wave 0..7
    const int hw   = blockIdx.x & 1;       // code half
    const int rg   = blockIdx.x >> 1;      // row group (256 rows)
    const int l31  = lane & 31;
    const int hi5  = lane >> 5;
    const int rowbase = rg * 256 + wv * 32;

    // ---- e2 half to LDS ----
    *(float4*)&e2s[t * 4] = *(const float4*)(e2 + hw * 2048 + t * 4);

    // ---- A panel (32 rows) to registers, hi/lo split ----
    f16x8 a_h[16], a_l[16];
    {
        const float* zr = z + (size_t)(rowbase + l31) * DIM + hi5 * 8;
        #pragma unroll
        for (int s = 0; s < 16; ++s) {
            float4 x0 = *(const float4*)(zr + s * 16);
            float4 x1 = *(const float4*)(zr + s * 16 + 4);
            float xs[8] = {x0.x, x0.y, x0.z, x0.w, x1.x, x1.y, x1.z, x1.w};
            #pragma unroll
            for (int j = 0; j < 8; ++j) {
                f16 h = (f16)xs[j];
                a_h[s][j] = h;
                a_l[s][j] = (f16)((xs[j] - (float)h) * LOSCALE);
            }
        }
    }

    const char* bhalf = bp + ((size_t)hw << 21);   // 2 MB half

    // stage col cc (32KB) into buffer pb: 512 thr x 4 x 16B, linear
#define STAGE(pb, cc) do {                                                    \
    const char* src_ = bhalf + ((size_t)(cc) << 15) + (size_t)t * 16;         \
    char* dst_ = bufs[pb] + t * 16;                                           \
    _Pragma("unroll")                                                         \
    for (int i_ = 0; i_ < 4; ++i_)                                            \
        GLOAD16(src_ + i_ * 8192, dst_ + i_ * 8192);                          \
    } while (0)

    STAGE(0, 0);
    STAGE(1, 1);
    __syncthreads();   // full drain once: cols 0,1 staged; e2s visible

    float    bestd[16];
    unsigned bcol[4];
    #pragma unroll
    for (int q = 0; q < 16; ++q) bestd[q] = 3.4e38f;
    #pragma unroll
    for (int i = 0; i < 4; ++i) bcol[i] = 0u;

    for (int c = 0; c < 64; ++c) {
        // stage col c+2 into the buffer last read at col c-2 (race-free:
        // every wave passed barrier c-1, which implies compute(c-2) done)
        STAGE((c + 2) & 3, c + 2);

        asm volatile("s_waitcnt vmcnt(8)" ::: "memory");   // col c's 4 done
        asm volatile("s_waitcnt lgkmcnt(0)" ::: "memory");
        __builtin_amdgcn_s_barrier();
        __builtin_amdgcn_sched_barrier(0);

        // 6 independent accumulator chains
        f32x16 m0, m1, c0, c1, c2, c3;
        #pragma unroll
        for (int q = 0; q < 16; ++q) {
            m0[q] = 0.0f; m1[q] = 0.0f;
            c0[q] = 0.0f; c1[q] = 0.0f; c2[q] = 0.0f; c3[q] = 0.0f;
        }

        const char* bb = bufs[c & 3];
        __builtin_amdgcn_s_setprio(1);
        #pragma unroll
        for (int ks = 0; ks < 16; ks += 2) {
            f16x8 bh0 = *(const f16x8*)(bb + ks * 2048 + lane * 16);
            f16x8 bl0 = *(const f16x8*)(bb + ks * 2048 + 1024 + lane * 16);
            f16x8 bh1 = *(const f16x8*)(bb + (ks + 1) * 2048 + lane * 16);
            f16x8 bl1 = *(const f16x8*)(bb + (ks + 1) * 2048 + 1024 + lane * 16);
            m0 = __builtin_amdgcn_mfma_f32_32x32x16_f16(a_h[ks],     bh0, m0, 0, 0, 0);
            c0 = __builtin_amdgcn_mfma_f32_32x32x16_f16(a_h[ks],     bl0, c0, 0, 0, 0);
            c1 = __builtin_amdgcn_mfma_f32_32x32x16_f16(a_l[ks],     bh0, c1, 0, 0, 0);
            m1 = __builtin_amdgcn_mfma_f32_32x32x16_f16(a_h[ks + 1], bh1, m1, 0, 0, 0);
            c2 = __builtin_amdgcn_mfma_f32_32x32x16_f16(a_h[ks + 1], bl1, c2, 0, 0, 0);
            c3 = __builtin_amdgcn_mfma_f32_32x32x16_f16(a_l[ks + 1], bh1, c3, 0, 0, 0);
        }
        __builtin_amdgcn_s_setprio(0);

        // epilogue: fold chains, distances, running argmin
        float e2c = e2s[c * 32 + l31];
        #pragma unroll
        for (int q = 0; q < 16; ++q) {
            float corr = (c0[q] + c1[q]) + (c2[q] + c3[q]);
            float dot  = fmaf(corr, INV_LOSCALE, m0[q] + m1[q]);
            float dist = fmaf(-2.0f, dot, e2c);
            bool  lt   = dist < bestd[q];
            bestd[q]   = lt ? dist : bestd[q];
            const unsigned sh = (unsigned)((q & 3) * 8);
            unsigned nv = (bcol[q >> 2] & ~(0xFFu << sh)) | ((unsigned)c << sh);
            bcol[q >> 2] = lt ? nv : bcol[q >> 2];
        }
    }
#undef STAGE

    // ---- per-wave reduce across 32 code-lanes; write partial keys ----
    #pragma unroll
    for (int q = 0; q < 16; ++q) {
        float    d = bestd[q];
        unsigned c = (unsigned)(hw * 2048) +
                     ((bcol[q >> 2] >> ((q & 3) * 8)) & 0xFFu) * 32u + (unsigned)l31;
        #pragma unroll
        for (int o2 = 16; o2; o2 >>= 1) {
            float    od = __shfl_xor(d, o2);
            unsigned oc = __shfl_xor(c, o2);
            if (od < d || (od == d && oc < c)) { d = od; c = oc; }
        }
        if (l31 == 0) {
            int row = (q & 3) + 8 * (q >> 2) + 4 * hi5;
            unsigned u   = __float_as_uint(d);
            unsigned key = u ^ (unsigned)(((int)u >> 31) | 0x80000000);
            part[(size_t)hw * 32768 + rowbase + row] =
                ((unsigned long long)key << 32) | c;
        }
    }
}

// fused: combine half-K partials -> idx, gather z_q row, histogram
__global__ void vq_final(const unsigned long long* __restrict__ part,
                         const float* __restrict__ emb,
                         float* __restrict__ idxf, float* __restrict__ zq,
                         int* __restrict__ counts, int N)
{
    int n = blockIdx.x * 4 + (threadIdx.x >> 6);
    int l = threadIdx.x & 63;
    if (n >= N) return;
    unsigned long long a = part[n];
    unsigned long long b = part[(size_t)N + n];
    unsigned long long m = b < a ? b : a;
    int idx = (int)(unsigned)(m & 0xffffffffu);
    ((float4*)(zq + (size_t)n * DIM))[l] =
        ((const float4*)(emb + (size_t)idx * DIM))[l];
    if (l == 0) {
        idxf[n] = (float)idx;
        atomicAdd(&counts[idx], 1);
    }
}

// ------------------------- round-1 fallback argmin -------------------------
__global__ __launch_bounds__(256, 2) void vq_argmin_f32(
    const float* __restrict__ z, const float* __restrict__ emb,
    const float* __restrict__ e2, float* __restrict__ idxf, int K)
{
    __shared__ float zs[64 * 36];
    __shared__ float es[128 * 36];
    const int t = threadIdx.x;
    const int tx = t & 15;
    const int ty = t >> 4;
    const int rowbase = blockIdx.x * 64;
    const float* zbase = z + (size_t)rowbase * DIM;
    float best[4]; int bidx[4];
    #pragma unroll
    for (int i = 0; i < 4; ++i) { best[i] = 3.4e38f; bidx[i] = 0; }
    for (int kt = 0; kt < K; kt += 128) {
        float acc[4][8];
        #pragma unroll
        for (int i = 0; i < 4; ++i)
            #pragma unroll
            for (int j = 0; j < 8; ++j) acc[i][j] = 0.0f;
        for (int dc = 0; dc < DIM; dc += 32) {
            { int lr = t >> 2, o = (t & 3) * 8;
              const float* gp = zbase + (size_t)lr * DIM + dc + o;
              *(float4*)&zs[lr*36+o]   = *(const float4*)gp;
              *(float4*)&zs[lr*36+o+4] = *(const float4*)(gp+4); }
            { int lc = t >> 1, o = (t & 1) * 16;
              const float* gp = emb + (size_t)(kt+lc) * DIM + dc + o;
              *(float4*)&es[lc*36+o]    = *(const float4*)gp;
              *(float4*)&es[lc*36+o+4]  = *(const float4*)(gp+4);
              *(float4*)&es[lc*36+o+8]  = *(const float4*)(gp+8);
              *(float4*)&es[lc*36+o+12] = *(const float4*)(gp+12); }
            __syncthreads();
            const float* zp = &zs[(ty*4)*36];
            const float* ep = &es[tx*36];
            #pragma unroll
            for (int d = 0; d < 32; d += 4) {
                float4 zv[4], ev[8];
                #pragma unroll
                for (int i = 0; i < 4; ++i) zv[i] = *(const float4*)&zp[i*36+d];
                #pragma unroll
                for (int j = 0; j < 8; ++j) ev[j] = *(const float4*)&ep[j*16*36+d];
                #pragma unroll
                for (int i = 0; i < 4; ++i)
                    #pragma unroll
                    for (int j = 0; j < 8; ++j) {
                        acc[i][j] += zv[i].x*ev[j].x; acc[i][j] += zv[i].y*ev[j].y;
                        acc[i][j] += zv[i].z*ev[j].z; acc[i][j] += zv[i].w*ev[j].w;
                    }
            }
            __syncthreads();
        }
        #pragma unroll
        for (int j = 0; j < 8; ++j) {
            int c = kt + tx + 16*j;
            float ev2 = e2[c];
            #pragma unroll
            for (int i = 0; i < 4; ++i) {
                float dist = ev2 - 2.0f*acc[i][j];
                if (dist < best[i] || (dist == best[i] && c < bidx[i])) { best[i]=dist; bidx[i]=c; }
            }
        }
    }
    #pragma unroll
    for (int i = 0; i < 4; ++i) {
        float bd = best[i]; int bi = bidx[i];
        #pragma unroll
        for (int off = 8; off; off >>= 1) {
            float od = __shfl_xor(bd, off); int oi = __shfl_xor(bi, off);
            if (od < bd || (od == bd && oi < bi)) { bd = od; bi = oi; }
        }
        if (tx == 0) idxf[rowbase + ty*4 + i] = (float)bi;
    }
}

// ------------------------------ epilogue ops -------------------------------
__global__ void vq_gather(const float* __restrict__ emb,
                          const float* __restrict__ idxf,
                          float* __restrict__ zq, int N)
{
    int n = blockIdx.x * 4 + (threadIdx.x >> 6);
    int l = threadIdx.x & 63;
    if (n >= N) return;
    int idx = (int)idxf[n];
    ((float4*)(zq + (size_t)n * DIM))[l] = ((const float4*)(emb + (size_t)idx * DIM))[l];
}

__global__ void vq_hist(const float* __restrict__ idxf, int* __restrict__ counts, int N) {
    int n = blockIdx.x * blockDim.x + threadIdx.x;
    if (n < N) atomicAdd(&counts[(int)idxf[n]], 1);
}

__global__ void vq_ppl(const int* __restrict__ counts, float invN,
                       float* __restrict__ out, int K)
{
    int t = threadIdx.x;
    float s = 0.0f;
    for (int k = t; k < K; k += 256) {
        float p = (float)counts[k] * invN;
        s += p * logf(p + 1e-10f);
    }
    #pragma unroll
    for (int off = 32; off; off >>= 1) s += __shfl_xor(s, off);
    __shared__ float wsum[4];
    if ((t & 63) == 0) wsum[t >> 6] = s;
    __syncthreads();
    if (t == 0) out[0] = expf(-(wsum[0] + wsum[1] + wsum[2] + wsum[3]));
}

extern "C" void kernel_launch(void* const* d_in, const int* in_sizes, int n_in,
                              void* d_out, int out_size, void* d_ws, size_t ws_size,
                              hipStream_t stream)
{
    const float* z   = (const float*)d_in[0];
    const float* emb = (const float*)d_in[1];
    const int N = in_sizes[0] / DIM;   // 32768
    const int K = in_sizes[1] / DIM;   // 4096

    float* out  = (float*)d_out;
    float* zq   = out;
    float* idxf = out + (size_t)N * DIM;
    float* ppl  = idxf + N;

    const size_t PART_BYTES = 2ull * 32768 * sizeof(unsigned long long);  // 512 KB
    const size_t NEED = (size_t)BP_BYTES + 16384 + 16384 + PART_BYTES;

    if (ws_size >= NEED && K == 4096 && N == 32768) {
        f16*   bpk    = (f16*)d_ws;
        float* e2     = (float*)((char*)d_ws + BP_BYTES);
        int*   counts = (int*)((char*)d_ws + BP_BYTES + 16384);
        unsigned long long* part =
            (unsigned long long*)((char*)d_ws + BP_BYTES + 32768);

        vq_pack2<<<1024, 256, 0, stream>>>(emb, bpk);
        vq_e2<<<K, 64, 0, stream>>>(emb, e2);
        vq_zero<<<(K + 255) / 256, 256, 0, stream>>>(counts, K);
        vq_argmin13<<<(N / 256) * 2, 512, 0, stream>>>(z, (const char*)bpk, e2, part);
        vq_final<<<N / 4, 256, 0, stream>>>(part, emb, idxf, zq, counts, N);
        vq_ppl<<<1, 256, 0, stream>>>(counts, 1.0f / (float)N, ppl, K);
    } else {
        float* e2     = (float*)d_ws;
        int*   counts = (int*)((char*)d_ws + (size_t)K * sizeof(float));
        vq_e2<<<K, 64, 0, stream>>>(emb, e2);
        vq_zero<<<(K + 255) / 256, 256, 0, stream>>>(counts, K);
        vq_argmin_f32<<<N / 64, 256, 0, stream>>>(z, emb, e2, idxf, K);
        vq_gather<<<N / 4, 256, 0, stream>>>(emb, idxf, zq, N);
        vq_hist<<<(N + 255) / 256, 256, 0, stream>>>(idxf, counts, N);
        vq_ppl<<<1, 256, 0, stream>>>(counts, 1.0f / (float)N, ppl, K);
    }
}